// Round 6
// baseline (529.935 us; speedup 1.0000x reference)
//
#include <hip/hip_runtime.h>
#include <hip/hip_bf16.h>
#include <stdint.h>

#define N_NODES 50000
#define N_EDGES 800000
#define N_GRAPHS 512

// ---------- helpers ----------
__device__ __forceinline__ unsigned f2sort(float f) {
    unsigned u = __float_as_uint(f);
    return (u & 0x80000000u) ? ~u : (u | 0x80000000u);   // monotonic f32 -> u32
}
__device__ __forceinline__ float sort2f(unsigned u) {
    return __uint_as_float((u & 0x80000000u) ? (u ^ 0x80000000u) : ~u);
}

// ---------- K0: per-graph edge histogram + node_start ----------
__global__ __launch_bounds__(256) void k0_init(const int* __restrict__ ei,
                                               const int* __restrict__ batch,
                                               unsigned* __restrict__ deg,
                                               int* __restrict__ node_start) {
    __shared__ unsigned hist[512];
    const int tid = threadIdx.x;
    hist[tid] = 0; hist[tid + 256] = 0;
    __syncthreads();
    int i = blockIdx.x * 256 + tid;                 // grid exact: 3125*256 == N_EDGES
    atomicAdd(&hist[batch[ei[i]]], 1u);
    if (i < N_NODES) {
        int b = batch[i];
        if (i == 0) { for (int g2 = 0; g2 <= b; ++g2) node_start[g2] = 0; }
        else { int bp = batch[i - 1]; for (int g2 = bp + 1; g2 <= b; ++g2) node_start[g2] = i; }
        if (i == N_NODES - 1) { for (int g2 = b + 1; g2 <= N_GRAPHS; ++g2) node_start[g2] = N_NODES; }
    }
    __syncthreads();
    if (hist[tid])       atomicAdd(&deg[tid],       hist[tid]);
    if (hist[tid + 256]) atomicAdd(&deg[tid + 256], hist[tid + 256]);
}

// ---------- K3: scan over 512 graph degrees ----------
__global__ __launch_bounds__(512) void k3_scan(const unsigned* __restrict__ deg,
                                               unsigned* __restrict__ start,
                                               unsigned* __restrict__ kk) {
    __shared__ unsigned lds[512];
    int t = threadIdx.x;
    unsigned d = deg[t];
    lds[t] = d;
    for (int off = 1; off < 512; off <<= 1) {
        __syncthreads();
        unsigned v = (t >= off) ? lds[t - off] : 0u;
        __syncthreads();
        lds[t] += v;
    }
    __syncthreads();
    start[t] = lds[t] - d;        // exclusive prefix
    kk[t]    = (d + 1u) >> 1;     // ceil(0.5*deg)
}

// ---------- K4a: two-level scatter into per-graph buckets ----------
__global__ __launch_bounds__(256) void k4a_scatter(const int* __restrict__ ei,
                                                   const int* __restrict__ batch,
                                                   const unsigned* __restrict__ start,
                                                   unsigned* __restrict__ cursor,
                                                   unsigned* __restrict__ rcbuck,
                                                   unsigned* __restrict__ ebuck,
                                                   unsigned* __restrict__ posOf) {
    __shared__ unsigned hist[512];
    __shared__ unsigned base[512];
    const int tid = threadIdx.x;
    const int e0 = blockIdx.x * 4096;
    hist[tid] = 0; hist[tid + 256] = 0;
    __syncthreads();
    #pragma unroll 4
    for (int j = 0; j < 16; ++j) {
        int e = e0 + j * 256 + tid;
        if (e < N_EDGES) atomicAdd(&hist[batch[ei[e]]], 1u);
    }
    __syncthreads();
    for (int g = tid; g < 512; g += 256) {
        unsigned h = hist[g];
        base[g] = h ? atomicAdd(&cursor[g], h) : 0u;
    }
    __syncthreads();
    hist[tid] = 0; hist[tid + 256] = 0;
    __syncthreads();
    #pragma unroll 4
    for (int j = 0; j < 16; ++j) {
        int e = e0 + j * 256 + tid;
        if (e < N_EDGES) {
            int r = ei[e], c = ei[N_EDGES + e];
            int g = batch[r];
            unsigned rank = atomicAdd(&hist[g], 1u);
            unsigned pos = start[g] + base[g] + rank;
            rcbuck[pos] = (unsigned)r | ((unsigned)c << 16);
            ebuck[pos]  = (unsigned)e;
            posOf[e]    = pos;
        }
    }
}

// ---------- K1: P = emb@W1a + b1, Q = emb@W1b ----------
__global__ __launch_bounds__(256) void k1_gemm(const float* __restrict__ emb,
                                               const float* __restrict__ W1,
                                               const float* __restrict__ b1,
                                               float* __restrict__ P,
                                               float* __restrict__ Q) {
    __shared__ float As[64][68];
    __shared__ float Bs[64][128];
    const int tid = threadIdx.x;
    const int v0  = blockIdx.x * 64;
    const int cy  = blockIdx.y;

    if (v0 + 64 <= N_NODES) {
        const float* srcA = emb + (size_t)v0 * 64;
        for (int idx = tid * 4; idx < 4096; idx += 1024) {
            float4 x = *(const float4*)(srcA + idx);
            int r = idx >> 6, k = idx & 63;
            As[k + 0][r] = x.x; As[k + 1][r] = x.y; As[k + 2][r] = x.z; As[k + 3][r] = x.w;
        }
    } else {
        for (int idx = tid * 4; idx < 4096; idx += 1024) {
            int r = idx >> 6, k = idx & 63;
            int v = v0 + r; if (v >= N_NODES) v = N_NODES - 1;
            float4 x = *(const float4*)(emb + (size_t)v * 64 + k);
            As[k + 0][r] = x.x; As[k + 1][r] = x.y; As[k + 2][r] = x.z; As[k + 3][r] = x.w;
        }
    }
    for (int idx = tid * 4; idx < 64 * 128; idx += 1024) {
        int k = idx >> 7, c = idx & 127;
        int jj = cy * 128 + c;
        const float* src = (jj < 256) ? (W1 + (size_t)k * 256 + jj)
                                      : (W1 + (size_t)(64 + k) * 256 + (jj - 256));
        *(float4*)&Bs[k][c] = *(const float4*)src;
    }
    __syncthreads();

    const int cgrp = tid & 31;
    const int rgrp = tid >> 5;
    float acc[8][4];
    #pragma unroll
    for (int r = 0; r < 8; ++r) { acc[r][0]=0.f; acc[r][1]=0.f; acc[r][2]=0.f; acc[r][3]=0.f; }

    #pragma unroll 8
    for (int k = 0; k < 64; ++k) {
        float4 b = *(const float4*)&Bs[k][cgrp * 4];
        const float4* ap = (const float4*)&As[k][rgrp * 8];
        float4 a01 = ap[0], a23 = ap[1];
        float av[8] = {a01.x, a01.y, a01.z, a01.w, a23.x, a23.y, a23.z, a23.w};
        #pragma unroll
        for (int r = 0; r < 8; ++r) {
            acc[r][0] = fmaf(av[r], b.x, acc[r][0]);
            acc[r][1] = fmaf(av[r], b.y, acc[r][1]);
            acc[r][2] = fmaf(av[r], b.z, acc[r][2]);
            acc[r][3] = fmaf(av[r], b.w, acc[r][3]);
        }
    }

    const int jj0 = cy * 128 + cgrp * 4;
    float4 badd = {0.f, 0.f, 0.f, 0.f};
    if (jj0 < 256) badd = *(const float4*)(b1 + jj0);
    #pragma unroll
    for (int r = 0; r < 8; ++r) {
        int v = v0 + rgrp * 8 + r;
        if (v < N_NODES) {
            float4 o = {acc[r][0] + badd.x, acc[r][1] + badd.y,
                        acc[r][2] + badd.z, acc[r][3] + badd.w};
            float* dst = (jj0 < 256) ? (P + (size_t)v * 256 + jj0)
                                     : (Q + (size_t)v * 256 + (jj0 - 256));
            *(float4*)dst = o;
        }
    }
}

// ---------- K2: per-graph scoring, 1024 threads (16 waves), P staged in LDS ----------
__global__ __launch_bounds__(1024, 8) void k2_edge(const float* __restrict__ P,
                                                   const float* __restrict__ Q,
                                                   const unsigned* __restrict__ rcbuck,
                                                   const unsigned* __restrict__ deg,
                                                   const unsigned* __restrict__ start,
                                                   const int* __restrict__ node_start,
                                                   const float* __restrict__ W2,
                                                   const float* __restrict__ b2,
                                                   float* __restrict__ attb,
                                                   unsigned* __restrict__ minmax,
                                                   int ldsrows) {
    extern __shared__ float4 lds4[];
    const int g = blockIdx.x;
    const int n = (int)deg[g];
    if (n == 0) return;
    const int st = (int)start[g];
    const int n0 = node_start[g];
    const int nr = node_start[g + 1] - n0;
    const int ncap = nr < ldsrows ? nr : ldsrows;
    const int tid = threadIdx.x;

    const float4* Pg4 = (const float4*)(P + (size_t)n0 * 256);
    for (int u = tid; u < ncap * 64; u += 1024) lds4[u] = Pg4[u];
    __syncthreads();

    const int lane = tid & 63;
    const int w = tid >> 6;          // 16 waves
    const int j0 = lane * 4;
    const float4 w2v = *(const float4*)(W2 + j0);
    const float b2v = b2[0];
    float vmin = __builtin_inff(), vmax = -__builtin_inff();

    const int nquads = (n + 3) >> 2;
    for (int qi = w; qi < nquads; qi += 16) {
        const int i0 = st + qi * 4;
        int cnt = n - qi * 4; if (cnt > 4) cnt = 4;
        unsigned rc0 = rcbuck[i0];
        unsigned rc1 = (cnt > 1) ? rcbuck[i0 + 1] : (unsigned)n0;
        unsigned rc2 = (cnt > 2) ? rcbuck[i0 + 2] : (unsigned)n0;
        unsigned rc3 = (cnt > 3) ? rcbuck[i0 + 3] : (unsigned)n0;
        int r0 = rc0 & 0xFFFFu, c0 = rc0 >> 16;
        int r1 = rc1 & 0xFFFFu, c1 = rc1 >> 16;
        int r2 = rc2 & 0xFFFFu, c2 = rc2 >> 16;
        int r3 = rc3 & 0xFFFFu, c3 = rc3 >> 16;

        int rl0 = r0 - n0, rl1 = r1 - n0, rl2 = r2 - n0, rl3 = r3 - n0;
        float4 p0 = (rl0 < ncap) ? lds4[rl0 * 64 + lane] : *(const float4*)(P + (size_t)r0 * 256 + j0);
        float4 p1 = (rl1 < ncap) ? lds4[rl1 * 64 + lane] : *(const float4*)(P + (size_t)r1 * 256 + j0);
        float4 p2 = (rl2 < ncap) ? lds4[rl2 * 64 + lane] : *(const float4*)(P + (size_t)r2 * 256 + j0);
        float4 p3 = (rl3 < ncap) ? lds4[rl3 * 64 + lane] : *(const float4*)(P + (size_t)r3 * 256 + j0);
        float4 q0 = *(const float4*)(Q + (size_t)c0 * 256 + j0);
        float4 q1 = *(const float4*)(Q + (size_t)c1 * 256 + j0);
        float4 q2 = *(const float4*)(Q + (size_t)c2 * 256 + j0);
        float4 q3 = *(const float4*)(Q + (size_t)c3 * 256 + j0);

        float part0, part1, part2, part3;
        {
            float s0 = fmaxf(p0.x + q0.x, 0.f), s1 = fmaxf(p0.y + q0.y, 0.f);
            float s2 = fmaxf(p0.z + q0.z, 0.f), s3 = fmaxf(p0.w + q0.w, 0.f);
            part0 = fmaf(s3, w2v.w, fmaf(s2, w2v.z, fmaf(s1, w2v.y, s0 * w2v.x)));
        }
        {
            float s0 = fmaxf(p1.x + q1.x, 0.f), s1 = fmaxf(p1.y + q1.y, 0.f);
            float s2 = fmaxf(p1.z + q1.z, 0.f), s3 = fmaxf(p1.w + q1.w, 0.f);
            part1 = fmaf(s3, w2v.w, fmaf(s2, w2v.z, fmaf(s1, w2v.y, s0 * w2v.x)));
        }
        {
            float s0 = fmaxf(p2.x + q2.x, 0.f), s1 = fmaxf(p2.y + q2.y, 0.f);
            float s2 = fmaxf(p2.z + q2.z, 0.f), s3 = fmaxf(p2.w + q2.w, 0.f);
            part2 = fmaf(s3, w2v.w, fmaf(s2, w2v.z, fmaf(s1, w2v.y, s0 * w2v.x)));
        }
        {
            float s0 = fmaxf(p3.x + q3.x, 0.f), s1 = fmaxf(p3.y + q3.y, 0.f);
            float s2 = fmaxf(p3.z + q3.z, 0.f), s3 = fmaxf(p3.w + q3.w, 0.f);
            part3 = fmaf(s3, w2v.w, fmaf(s2, w2v.z, fmaf(s1, w2v.y, s0 * w2v.x)));
        }
        #pragma unroll
        for (int off = 32; off; off >>= 1) {
            part0 += __shfl_xor(part0, off, 64);
            part1 += __shfl_xor(part1, off, 64);
            part2 += __shfl_xor(part2, off, 64);
            part3 += __shfl_xor(part3, off, 64);
        }
        float a0 = part0 + b2v, a1 = part1 + b2v, a2 = part2 + b2v, a3 = part3 + b2v;
        if (lane == 0)                   attb[i0]     = a0;
        else if (lane == 1 && cnt > 1)   attb[i0 + 1] = a1;
        else if (lane == 2 && cnt > 2)   attb[i0 + 2] = a2;
        else if (lane == 3 && cnt > 3)   attb[i0 + 3] = a3;
        vmin = fminf(vmin, a0); vmax = fmaxf(vmax, a0);
        if (cnt > 1) { vmin = fminf(vmin, a1); vmax = fmaxf(vmax, a1); }
        if (cnt > 2) { vmin = fminf(vmin, a2); vmax = fmaxf(vmax, a2); }
        if (cnt > 3) { vmin = fminf(vmin, a3); vmax = fmaxf(vmax, a3); }
    }
    if (lane == 0) {
        atomicMin(&minmax[0], f2sort(vmin));
        atomicMax(&minmax[1], f2sort(vmax));
    }
}

// ---------- K5: radix-select top-K per graph (exact (key,e) order semantics) ----------
__global__ __launch_bounds__(256) void k5_select(const unsigned* __restrict__ deg,
                                                 const unsigned* __restrict__ start,
                                                 const unsigned* __restrict__ kk,
                                                 const float* __restrict__ attb,
                                                 const unsigned* __restrict__ ebuck,
                                                 const unsigned* __restrict__ rcbuck,
                                                 const unsigned* __restrict__ minmax,
                                                 unsigned char* __restrict__ keepb,
                                                 unsigned char* __restrict__ flagC,
                                                 unsigned char* __restrict__ flagS) {
    __shared__ unsigned kbuf[4096];
    __shared__ unsigned hist[256];
    __shared__ unsigned sh_b, sh_excl, sh_cnt;
    const int g = blockIdx.x, t = threadIdx.x;
    int n = (int)deg[g]; if (n > 4096) n = 4096;
    if (n == 0) return;
    const unsigned st = start[g];
    const float fmin = sort2f(minmax[0]);
    const float fmax = sort2f(minmax[1]);
    const float denom = (fmax - fmin) + 1e-12f;
    const float gf = (float)g;
    for (int i = t; i < n; i += 256) {
        float a = attb[st + i];
        float nq = (a - fmin) / denom;       // replicate ref f32 division
        float mq = nq - gf;                  // replicate ref's quantizing subtraction
        kbuf[i] = ~f2sort(mq);               // ascending == ref's descending-norm order
    }
    const unsigned K = kk[g];                // 1..n

    // --- select K-th smallest key (MSB radix, 4 passes) ---
    unsigned lo = 0, prefix = 0, meq = 0;
    for (int byte = 3; byte >= 0; --byte) {
        __syncthreads();
        hist[t] = 0;
        __syncthreads();
        const int shAbove = (byte + 1) * 8;
        for (int i = t; i < n; i += 256) {
            unsigned k = kbuf[i];
            bool ok = (byte == 3) || ((k >> shAbove) == (prefix >> shAbove));
            if (ok) atomicAdd(&hist[(k >> (byte * 8)) & 0xFFu], 1u);
        }
        __syncthreads();
        unsigned v = hist[t];
        for (int off = 1; off < 256; off <<= 1) {
            __syncthreads();
            unsigned u = (t >= off) ? hist[t - off] : 0u;
            __syncthreads();
            hist[t] += u;
        }
        __syncthreads();
        unsigned incl = hist[t], excl = incl - v;
        unsigned target = K - lo;            // >= 1
        if (excl < target && target <= incl) { sh_b = (unsigned)t; sh_excl = excl; sh_cnt = v; }
        __syncthreads();
        prefix |= sh_b << (byte * 8);
        lo += sh_excl;
        meq = sh_cnt;
    }
    const unsigned T32 = prefix;
    const unsigned tneed = K - lo;           // 1..meq
    bool keepAllTies = (tneed == meq);

    // --- among ties (key==T32), select tneed-th smallest e (3 passes; e < 2^20) ---
    unsigned E_t = 0xFFFFFFFFu;
    if (!keepAllTies) {
        unsigned elo = 0, eprefix = 0;
        for (int byte = 2; byte >= 0; --byte) {
            __syncthreads();
            hist[t] = 0;
            __syncthreads();
            const int shAbove = (byte + 1) * 8;
            for (int i = t; i < n; i += 256) {
                if (kbuf[i] == T32) {
                    unsigned e = ebuck[st + i];
                    bool ok = (byte == 2) || ((e >> shAbove) == (eprefix >> shAbove));
                    if (ok) atomicAdd(&hist[(e >> (byte * 8)) & 0xFFu], 1u);
                }
            }
            __syncthreads();
            unsigned v = hist[t];
            for (int off = 1; off < 256; off <<= 1) {
                __syncthreads();
                unsigned u = (t >= off) ? hist[t - off] : 0u;
                __syncthreads();
                hist[t] += u;
            }
            __syncthreads();
            unsigned incl = hist[t], excl = incl - v;
            unsigned target = tneed - elo;
            if (excl < target && target <= incl) { sh_b = (unsigned)t; sh_excl = excl; }
            __syncthreads();
            eprefix |= sh_b << (byte * 8);
            elo += sh_excl;
        }
        E_t = eprefix;                       // tneed-th smallest e among ties
    }

    // --- mark keep + endpoint flags ---
    __syncthreads();
    for (int i = t; i < n; i += 256) {
        unsigned k = kbuf[i];
        bool kp = (k < T32) || (k == T32 && (keepAllTies || ebuck[st + i] <= E_t));
        keepb[st + i] = kp ? 1 : 0;
        unsigned rc = rcbuck[st + i];
        int r = (int)(rc & 0xFFFFu), c = (int)(rc >> 16);
        if (kp) { flagC[r] = 1; flagC[c] = 1; }
        else    { flagS[r] = 1; flagS[c] = 1; }
    }
}

// ---------- K7: node-id compaction scan ----------
__global__ __launch_bounds__(1024) void k7_nodescan(const unsigned char* __restrict__ flagC,
                                                    const unsigned char* __restrict__ flagS,
                                                    int* __restrict__ nidxC,
                                                    int* __restrict__ nidxS) {
    const unsigned char* fl = blockIdx.x ? flagS : flagC;
    int* nx = blockIdx.x ? nidxS : nidxC;
    __shared__ int lds[1024];
    const int t = threadIdx.x;
    const int CH = (N_NODES + 1023) / 1024;   // 49
    const int base = t * CH;
    int s = 0;
    for (int i = 0; i < CH; ++i) { int v = base + i; if (v < N_NODES) s += fl[v]; }
    lds[t] = s;
    for (int off = 1; off < 1024; off <<= 1) {
        __syncthreads();
        int v = (t >= off) ? lds[t - off] : 0;
        __syncthreads();
        lds[t] += v;
    }
    __syncthreads();
    int run = lds[t] - s;
    for (int i = 0; i < CH; ++i) {
        int v = base + i;
        if (v < N_NODES) {
            if (fl[v]) { nx[v] = run; run++; } else nx[v] = -1;
        }
    }
}

// ---------- K8: outputs, iterated by e (all writes coalesced) ----------
__global__ __launch_bounds__(256) void k8_out(const float* __restrict__ attb,
                                              const unsigned char* __restrict__ keepb,
                                              const unsigned* __restrict__ posOf,
                                              const int* __restrict__ ei,
                                              const int* __restrict__ nidxC,
                                              const int* __restrict__ nidxS,
                                              float* __restrict__ out) {
    int e = blockIdx.x * 256 + threadIdx.x;       // grid exact
    unsigned pos = posOf[e];
    float a = attb[pos];                           // 3.2 MB array, L2-resident gather
    int kp = keepb[pos];
    int r = ei[e], c = ei[N_EDGES + e];
    out[e]               = a;
    out[N_EDGES + e]     = kp ? a : 0.f;
    out[2 * N_EDGES + e] = kp ? 0.f : -a;
    if (kp) {
        out[3 * N_EDGES + e] = (float)nidxC[r];
        out[4 * N_EDGES + e] = (float)nidxC[c];
        out[5 * N_EDGES + e] = -1.f;
        out[6 * N_EDGES + e] = -1.f;
    } else {
        out[3 * N_EDGES + e] = -1.f;
        out[4 * N_EDGES + e] = -1.f;
        out[5 * N_EDGES + e] = (float)nidxS[r];
        out[6 * N_EDGES + e] = (float)nidxS[c];
    }
}

extern "C" void kernel_launch(void* const* d_in, const int* in_sizes, int n_in,
                              void* d_out, int out_size, void* d_ws, size_t ws_size,
                              hipStream_t stream) {
    const float* emb   = (const float*)d_in[0];
    const int*   ei    = (const int*)d_in[1];
    const int*   batch = (const int*)d_in[2];
    const float* W1    = (const float*)d_in[3];
    const float* b1    = (const float*)d_in[4];
    const float* W2    = (const float*)d_in[5];
    const float* b2    = (const float*)d_in[6];
    float* out = (float*)d_out;

    char* ws = (char*)d_ws;
    size_t off = 0;
    auto alloc = [&](size_t bytes) -> void* {
        off = (off + 255) & ~(size_t)255;
        void* p = ws + off;
        off += bytes;
        return p;
    };

    float* P              = (float*)alloc((size_t)N_NODES * 256 * 4);   // 51.2 MB
    float* Q              = (float*)alloc((size_t)N_NODES * 256 * 4);   // 51.2 MB
    float* attb           = (float*)alloc((size_t)N_EDGES * 4);
    unsigned* rcbuck      = (unsigned*)alloc(((size_t)N_EDGES + 8) * 4);
    unsigned* ebuck       = (unsigned*)alloc(((size_t)N_EDGES + 8) * 4);
    unsigned* posOf       = (unsigned*)alloc((size_t)N_EDGES * 4);
    unsigned char* keepb  = (unsigned char*)alloc(N_EDGES);
    unsigned char* flags2 = (unsigned char*)alloc((size_t)2 * N_NODES);  // C|S contiguous
    unsigned char* flagC  = flags2;
    unsigned char* flagS  = flags2 + N_NODES;
    int* nidxC            = (int*)alloc((size_t)N_NODES * 4);
    int* nidxS            = (int*)alloc((size_t)N_NODES * 4);
    // meta block: deg(512) start(512) kk(512) cursor(512) minmax(2) — one zero-memset
    unsigned* meta        = (unsigned*)alloc((4 * 512 + 2) * 4);
    unsigned* deg         = meta;
    unsigned* start       = meta + 512;
    unsigned* kk          = meta + 1024;
    unsigned* cursor      = meta + 1536;
    unsigned* minmax      = meta + 2048;
    int* node_start       = (int*)alloc(513 * 4);

    const int EB = (N_EDGES + 255) / 256;       // 3125 (exact)
    const int SB = (N_EDGES + 4095) / 4096;     // 196 scatter blocks

    hipMemsetAsync(meta, 0, (4 * 512 + 2) * 4, stream);
    hipMemsetAsync(minmax, 0xFF, 4, stream);                  // min acc = UINT_MAX
    hipMemsetAsync(flags2, 0, (size_t)2 * N_NODES, stream);

    int ldsrows = 78;                                         // 78 KB -> 2 blocks/CU
    if (hipFuncSetAttribute((const void*)k2_edge,
                            hipFuncAttributeMaxDynamicSharedMemorySize,
                            78 * 1024) != hipSuccess) {
        ldsrows = 56;
    }
    const size_t shbytes = (size_t)ldsrows * 1024;

    k0_init<<<EB, 256, 0, stream>>>(ei, batch, deg, node_start);
    k3_scan<<<1, 512, 0, stream>>>(deg, start, kk);
    k4a_scatter<<<SB, 256, 0, stream>>>(ei, batch, start, cursor, rcbuck, ebuck, posOf);

    dim3 g1((N_NODES + 63) / 64, 4);
    k1_gemm<<<g1, 256, 0, stream>>>(emb, W1, b1, P, Q);

    k2_edge<<<N_GRAPHS, 1024, shbytes, stream>>>(P, Q, rcbuck, deg, start,
                                                 node_start, W2, b2, attb, minmax, ldsrows);

    k5_select<<<N_GRAPHS, 256, 0, stream>>>(deg, start, kk, attb, ebuck, rcbuck,
                                            minmax, keepb, flagC, flagS);
    k7_nodescan<<<2, 1024, 0, stream>>>(flagC, flagS, nidxC, nidxS);
    k8_out<<<EB, 256, 0, stream>>>(attb, keepb, posOf, ei, nidxC, nidxS, out);
}

// Round 7
// 406.269 us; speedup vs baseline: 1.3044x; 1.3044x over previous
//
#include <hip/hip_runtime.h>
#include <hip/hip_bf16.h>
#include <stdint.h>

#define N_NODES 50000
#define N_EDGES 800000
#define N_GRAPHS 512
#define NSUB 16            // c-subbuckets per graph (c>>12, c<50000 -> 0..12)
#define NBUCK (N_GRAPHS * NSUB)   // 8192

// ---------- helpers ----------
__device__ __forceinline__ unsigned f2sort(float f) {
    unsigned u = __float_as_uint(f);
    return (u & 0x80000000u) ? ~u : (u | 0x80000000u);   // monotonic f32 -> u32
}
__device__ __forceinline__ float sort2f(unsigned u) {
    return __uint_as_float((u & 0x80000000u) ? (u ^ 0x80000000u) : ~u);
}

// ---------- K0: (g, c-window) histogram + node_start ----------
__global__ __launch_bounds__(256) void k0_count(const int* __restrict__ ei,
                                                const int* __restrict__ batch,
                                                unsigned* __restrict__ subdeg,
                                                int* __restrict__ node_start) {
    __shared__ unsigned hist[NBUCK];       // 32 KB
    const int tid = threadIdx.x;
    for (int i = tid; i < NBUCK; i += 256) hist[i] = 0;
    __syncthreads();
    const int e0 = blockIdx.x * 4096;
    #pragma unroll 4
    for (int j = 0; j < 16; ++j) {
        int e = e0 + j * 256 + tid;
        if (e < N_EDGES) {
            int r = ei[e], c = ei[N_EDGES + e];
            atomicAdd(&hist[batch[r] * NSUB + (c >> 12)], 1u);
        }
    }
    #pragma unroll 4
    for (int j = 0; j < 16; ++j) {
        int i = e0 + j * 256 + tid;
        if (i < N_NODES) {
            int b = batch[i];
            if (i == 0) { for (int g2 = 0; g2 <= b; ++g2) node_start[g2] = 0; }
            else { int bp = batch[i - 1]; for (int g2 = bp + 1; g2 <= b; ++g2) node_start[g2] = i; }
            if (i == N_NODES - 1) { for (int g2 = b + 1; g2 <= N_GRAPHS; ++g2) node_start[g2] = N_NODES; }
        }
    }
    __syncthreads();
    for (int i = tid; i < NBUCK; i += 256) {
        unsigned h = hist[i];
        if (h) atomicAdd(&subdeg[i], h);
    }
}

// ---------- K3: scan 8192 subbucket counts; derive per-graph deg/start/kk ----------
__global__ __launch_bounds__(1024) void k3_scan(const unsigned* __restrict__ subdeg,
                                                unsigned* __restrict__ substart,
                                                unsigned* __restrict__ deg,
                                                unsigned* __restrict__ start,
                                                unsigned* __restrict__ kkv) {
    __shared__ unsigned lds[1024];
    const int t = threadIdx.x;
    unsigned v[8], s = 0;
    #pragma unroll
    for (int j = 0; j < 8; ++j) { v[j] = subdeg[t * 8 + j]; s += v[j]; }
    lds[t] = s;
    for (int off = 1; off < 1024; off <<= 1) {
        __syncthreads();
        unsigned u = (t >= off) ? lds[t - off] : 0u;
        __syncthreads();
        lds[t] += u;
    }
    __syncthreads();
    unsigned run = lds[t] - s;             // exclusive prefix
    #pragma unroll
    for (int j = 0; j < 8; ++j) { substart[t * 8 + j] = run; run += v[j]; }
    if (t == 1023) substart[NBUCK] = lds[1023];   // total == N_EDGES
    __syncthreads();
    if (t < N_GRAPHS) {
        unsigned st0 = substart[t * NSUB];
        unsigned d = substart[(t + 1) * NSUB] - st0;
        start[t] = st0;
        deg[t] = d;
        kkv[t] = (d + 1u) >> 1;            // ceil(0.5*deg)
    }
}

// ---------- K4a: scatter edges into (g, c-window) buckets ----------
__global__ __launch_bounds__(256) void k4a_scatter(const int* __restrict__ ei,
                                                   const int* __restrict__ batch,
                                                   const unsigned* __restrict__ substart,
                                                   unsigned* __restrict__ subcursor,
                                                   unsigned* __restrict__ rcbuck,
                                                   unsigned* __restrict__ ebuck,
                                                   unsigned* __restrict__ posOf) {
    int e = blockIdx.x * 256 + threadIdx.x;         // grid exact
    int r = ei[e], c = ei[N_EDGES + e];
    int b = batch[r] * NSUB + (c >> 12);
    unsigned rank = atomicAdd(&subcursor[b], 1u);
    unsigned pos = substart[b] + rank;
    rcbuck[pos] = (unsigned)r | ((unsigned)c << 16);
    ebuck[pos]  = (unsigned)e;
    posOf[e]    = pos;
}

// ---------- K1: P = emb@W1a + b1, Q = emb@W1b ----------
__global__ __launch_bounds__(256) void k1_gemm(const float* __restrict__ emb,
                                               const float* __restrict__ W1,
                                               const float* __restrict__ b1,
                                               float* __restrict__ P,
                                               float* __restrict__ Q) {
    __shared__ float As[64][68];
    __shared__ float Bs[64][128];
    const int tid = threadIdx.x;
    const int v0  = blockIdx.x * 64;
    const int cy  = blockIdx.y;

    if (v0 + 64 <= N_NODES) {
        const float* srcA = emb + (size_t)v0 * 64;
        for (int idx = tid * 4; idx < 4096; idx += 1024) {
            float4 x = *(const float4*)(srcA + idx);
            int r = idx >> 6, k = idx & 63;
            As[k + 0][r] = x.x; As[k + 1][r] = x.y; As[k + 2][r] = x.z; As[k + 3][r] = x.w;
        }
    } else {
        for (int idx = tid * 4; idx < 4096; idx += 1024) {
            int r = idx >> 6, k = idx & 63;
            int v = v0 + r; if (v >= N_NODES) v = N_NODES - 1;
            float4 x = *(const float4*)(emb + (size_t)v * 64 + k);
            As[k + 0][r] = x.x; As[k + 1][r] = x.y; As[k + 2][r] = x.z; As[k + 3][r] = x.w;
        }
    }
    for (int idx = tid * 4; idx < 64 * 128; idx += 1024) {
        int k = idx >> 7, c = idx & 127;
        int jj = cy * 128 + c;
        const float* src = (jj < 256) ? (W1 + (size_t)k * 256 + jj)
                                      : (W1 + (size_t)(64 + k) * 256 + (jj - 256));
        *(float4*)&Bs[k][c] = *(const float4*)src;
    }
    __syncthreads();

    const int cgrp = tid & 31;
    const int rgrp = tid >> 5;
    float acc[8][4];
    #pragma unroll
    for (int r = 0; r < 8; ++r) { acc[r][0]=0.f; acc[r][1]=0.f; acc[r][2]=0.f; acc[r][3]=0.f; }

    #pragma unroll 8
    for (int k = 0; k < 64; ++k) {
        float4 b = *(const float4*)&Bs[k][cgrp * 4];
        const float4* ap = (const float4*)&As[k][rgrp * 8];
        float4 a01 = ap[0], a23 = ap[1];
        float av[8] = {a01.x, a01.y, a01.z, a01.w, a23.x, a23.y, a23.z, a23.w};
        #pragma unroll
        for (int r = 0; r < 8; ++r) {
            acc[r][0] = fmaf(av[r], b.x, acc[r][0]);
            acc[r][1] = fmaf(av[r], b.y, acc[r][1]);
            acc[r][2] = fmaf(av[r], b.z, acc[r][2]);
            acc[r][3] = fmaf(av[r], b.w, acc[r][3]);
        }
    }

    const int jj0 = cy * 128 + cgrp * 4;
    float4 badd = {0.f, 0.f, 0.f, 0.f};
    if (jj0 < 256) badd = *(const float4*)(b1 + jj0);
    #pragma unroll
    for (int r = 0; r < 8; ++r) {
        int v = v0 + rgrp * 8 + r;
        if (v < N_NODES) {
            float4 o = {acc[r][0] + badd.x, acc[r][1] + badd.y,
                        acc[r][2] + badd.z, acc[r][3] + badd.w};
            float* dst = (jj0 < 256) ? (P + (size_t)v * 256 + jj0)
                                     : (Q + (size_t)v * 256 + (jj0 - 256));
            *(float4*)dst = o;
        }
    }
}

// ---------- K2: per-graph scoring, 512 threads, P staged in LDS (R5 config) ----------
__global__ __launch_bounds__(512) void k2_edge(const float* __restrict__ P,
                                               const float* __restrict__ Q,
                                               const unsigned* __restrict__ rcbuck,
                                               const unsigned* __restrict__ deg,
                                               const unsigned* __restrict__ start,
                                               const int* __restrict__ node_start,
                                               const float* __restrict__ W2,
                                               const float* __restrict__ b2,
                                               float* __restrict__ attb,
                                               unsigned* __restrict__ minmax,
                                               int ldsrows) {
    extern __shared__ float4 lds4[];
    const int g = blockIdx.x;
    const int n = (int)deg[g];
    if (n == 0) return;
    const int st = (int)start[g];
    const int n0 = node_start[g];
    const int nr = node_start[g + 1] - n0;
    const int ncap = nr < ldsrows ? nr : ldsrows;
    const int tid = threadIdx.x;

    const float4* Pg4 = (const float4*)(P + (size_t)n0 * 256);
    for (int u = tid; u < ncap * 64; u += 512) lds4[u] = Pg4[u];
    __syncthreads();

    const int lane = tid & 63;
    const int w = tid >> 6;          // 8 waves
    const int j0 = lane * 4;
    const float4 w2v = *(const float4*)(W2 + j0);
    const float b2v = b2[0];
    float vmin = __builtin_inff(), vmax = -__builtin_inff();

    const int nquads = (n + 3) >> 2;
    for (int qi = w; qi < nquads; qi += 8) {
        const int i0 = st + qi * 4;
        int cnt = n - qi * 4; if (cnt > 4) cnt = 4;
        unsigned rc0 = rcbuck[i0];
        unsigned rc1 = (cnt > 1) ? rcbuck[i0 + 1] : (unsigned)n0;
        unsigned rc2 = (cnt > 2) ? rcbuck[i0 + 2] : (unsigned)n0;
        unsigned rc3 = (cnt > 3) ? rcbuck[i0 + 3] : (unsigned)n0;
        int r0 = rc0 & 0xFFFFu, c0 = rc0 >> 16;
        int r1 = rc1 & 0xFFFFu, c1 = rc1 >> 16;
        int r2 = rc2 & 0xFFFFu, c2 = rc2 >> 16;
        int r3 = rc3 & 0xFFFFu, c3 = rc3 >> 16;

        int rl0 = r0 - n0, rl1 = r1 - n0, rl2 = r2 - n0, rl3 = r3 - n0;
        float4 p0 = (rl0 < ncap) ? lds4[rl0 * 64 + lane] : *(const float4*)(P + (size_t)r0 * 256 + j0);
        float4 p1 = (rl1 < ncap) ? lds4[rl1 * 64 + lane] : *(const float4*)(P + (size_t)r1 * 256 + j0);
        float4 p2 = (rl2 < ncap) ? lds4[rl2 * 64 + lane] : *(const float4*)(P + (size_t)r2 * 256 + j0);
        float4 p3 = (rl3 < ncap) ? lds4[rl3 * 64 + lane] : *(const float4*)(P + (size_t)r3 * 256 + j0);
        float4 q0 = *(const float4*)(Q + (size_t)c0 * 256 + j0);
        float4 q1 = *(const float4*)(Q + (size_t)c1 * 256 + j0);
        float4 q2 = *(const float4*)(Q + (size_t)c2 * 256 + j0);
        float4 q3 = *(const float4*)(Q + (size_t)c3 * 256 + j0);

        float part0, part1, part2, part3;
        {
            float s0 = fmaxf(p0.x + q0.x, 0.f), s1 = fmaxf(p0.y + q0.y, 0.f);
            float s2 = fmaxf(p0.z + q0.z, 0.f), s3 = fmaxf(p0.w + q0.w, 0.f);
            part0 = fmaf(s3, w2v.w, fmaf(s2, w2v.z, fmaf(s1, w2v.y, s0 * w2v.x)));
        }
        {
            float s0 = fmaxf(p1.x + q1.x, 0.f), s1 = fmaxf(p1.y + q1.y, 0.f);
            float s2 = fmaxf(p1.z + q1.z, 0.f), s3 = fmaxf(p1.w + q1.w, 0.f);
            part1 = fmaf(s3, w2v.w, fmaf(s2, w2v.z, fmaf(s1, w2v.y, s0 * w2v.x)));
        }
        {
            float s0 = fmaxf(p2.x + q2.x, 0.f), s1 = fmaxf(p2.y + q2.y, 0.f);
            float s2 = fmaxf(p2.z + q2.z, 0.f), s3 = fmaxf(p2.w + q2.w, 0.f);
            part2 = fmaf(s3, w2v.w, fmaf(s2, w2v.z, fmaf(s1, w2v.y, s0 * w2v.x)));
        }
        {
            float s0 = fmaxf(p3.x + q3.x, 0.f), s1 = fmaxf(p3.y + q3.y, 0.f);
            float s2 = fmaxf(p3.z + q3.z, 0.f), s3 = fmaxf(p3.w + q3.w, 0.f);
            part3 = fmaf(s3, w2v.w, fmaf(s2, w2v.z, fmaf(s1, w2v.y, s0 * w2v.x)));
        }
        #pragma unroll
        for (int off = 32; off; off >>= 1) {
            part0 += __shfl_xor(part0, off, 64);
            part1 += __shfl_xor(part1, off, 64);
            part2 += __shfl_xor(part2, off, 64);
            part3 += __shfl_xor(part3, off, 64);
        }
        float a0 = part0 + b2v, a1 = part1 + b2v, a2 = part2 + b2v, a3 = part3 + b2v;
        if (lane == 0)                   attb[i0]     = a0;
        else if (lane == 1 && cnt > 1)   attb[i0 + 1] = a1;
        else if (lane == 2 && cnt > 2)   attb[i0 + 2] = a2;
        else if (lane == 3 && cnt > 3)   attb[i0 + 3] = a3;
        vmin = fminf(vmin, a0); vmax = fmaxf(vmax, a0);
        if (cnt > 1) { vmin = fminf(vmin, a1); vmax = fmaxf(vmax, a1); }
        if (cnt > 2) { vmin = fminf(vmin, a2); vmax = fmaxf(vmax, a2); }
        if (cnt > 3) { vmin = fminf(vmin, a3); vmax = fmaxf(vmax, a3); }
    }
    if (lane == 0) {
        atomicMin(&minmax[0], f2sort(vmin));
        atomicMax(&minmax[1], f2sort(vmax));
    }
}

// ---------- K5: radix-select top-K per graph (exact (key,e) order semantics) ----------
__global__ __launch_bounds__(256) void k5_select(const unsigned* __restrict__ deg,
                                                 const unsigned* __restrict__ start,
                                                 const unsigned* __restrict__ kk,
                                                 const float* __restrict__ attb,
                                                 const unsigned* __restrict__ ebuck,
                                                 const unsigned* __restrict__ rcbuck,
                                                 const unsigned* __restrict__ minmax,
                                                 unsigned char* __restrict__ keepb,
                                                 unsigned char* __restrict__ flagC,
                                                 unsigned char* __restrict__ flagS) {
    __shared__ unsigned kbuf[4096];
    __shared__ unsigned hist[256];
    __shared__ unsigned sh_b, sh_excl, sh_cnt;
    const int g = blockIdx.x, t = threadIdx.x;
    int n = (int)deg[g]; if (n > 4096) n = 4096;
    if (n == 0) return;
    const unsigned st = start[g];
    const float fmin = sort2f(minmax[0]);
    const float fmax = sort2f(minmax[1]);
    const float denom = (fmax - fmin) + 1e-12f;
    const float gf = (float)g;
    for (int i = t; i < n; i += 256) {
        float a = attb[st + i];
        float nq = (a - fmin) / denom;       // replicate ref f32 division
        float mq = nq - gf;                  // replicate ref's quantizing subtraction
        kbuf[i] = ~f2sort(mq);               // ascending == ref's descending-norm order
    }
    const unsigned K = kk[g];                // 1..n

    // --- select K-th smallest key (MSB radix, 4 passes) ---
    unsigned lo = 0, prefix = 0, meq = 0;
    for (int byte = 3; byte >= 0; --byte) {
        __syncthreads();
        hist[t] = 0;
        __syncthreads();
        const int shAbove = (byte + 1) * 8;
        for (int i = t; i < n; i += 256) {
            unsigned k = kbuf[i];
            bool ok = (byte == 3) || ((k >> shAbove) == (prefix >> shAbove));
            if (ok) atomicAdd(&hist[(k >> (byte * 8)) & 0xFFu], 1u);
        }
        __syncthreads();
        unsigned v = hist[t];
        for (int off = 1; off < 256; off <<= 1) {
            __syncthreads();
            unsigned u = (t >= off) ? hist[t - off] : 0u;
            __syncthreads();
            hist[t] += u;
        }
        __syncthreads();
        unsigned incl = hist[t], excl = incl - v;
        unsigned target = K - lo;            // >= 1
        if (excl < target && target <= incl) { sh_b = (unsigned)t; sh_excl = excl; sh_cnt = v; }
        __syncthreads();
        prefix |= sh_b << (byte * 8);
        lo += sh_excl;
        meq = sh_cnt;
    }
    const unsigned T32 = prefix;
    const unsigned tneed = K - lo;           // 1..meq
    bool keepAllTies = (tneed == meq);

    // --- among ties (key==T32), select tneed-th smallest e (3 passes; e < 2^20) ---
    unsigned E_t = 0xFFFFFFFFu;
    if (!keepAllTies) {
        unsigned elo = 0, eprefix = 0;
        for (int byte = 2; byte >= 0; --byte) {
            __syncthreads();
            hist[t] = 0;
            __syncthreads();
            const int shAbove = (byte + 1) * 8;
            for (int i = t; i < n; i += 256) {
                if (kbuf[i] == T32) {
                    unsigned e = ebuck[st + i];
                    bool ok = (byte == 2) || ((e >> shAbove) == (eprefix >> shAbove));
                    if (ok) atomicAdd(&hist[(e >> (byte * 8)) & 0xFFu], 1u);
                }
            }
            __syncthreads();
            unsigned v = hist[t];
            for (int off = 1; off < 256; off <<= 1) {
                __syncthreads();
                unsigned u = (t >= off) ? hist[t - off] : 0u;
                __syncthreads();
                hist[t] += u;
            }
            __syncthreads();
            unsigned incl = hist[t], excl = incl - v;
            unsigned target = tneed - elo;
            if (excl < target && target <= incl) { sh_b = (unsigned)t; sh_excl = excl; }
            __syncthreads();
            eprefix |= sh_b << (byte * 8);
            elo += sh_excl;
        }
        E_t = eprefix;                       // tneed-th smallest e among ties
    }

    // --- mark keep + endpoint flags ---
    __syncthreads();
    for (int i = t; i < n; i += 256) {
        unsigned k = kbuf[i];
        bool kp = (k < T32) || (k == T32 && (keepAllTies || ebuck[st + i] <= E_t));
        keepb[st + i] = kp ? 1 : 0;
        unsigned rc = rcbuck[st + i];
        int r = (int)(rc & 0xFFFFu), c = (int)(rc >> 16);
        if (kp) { flagC[r] = 1; flagC[c] = 1; }
        else    { flagS[r] = 1; flagS[c] = 1; }
    }
}

// ---------- K7: node-id compaction scan ----------
__global__ __launch_bounds__(1024) void k7_nodescan(const unsigned char* __restrict__ flagC,
                                                    const unsigned char* __restrict__ flagS,
                                                    int* __restrict__ nidxC,
                                                    int* __restrict__ nidxS) {
    const unsigned char* fl = blockIdx.x ? flagS : flagC;
    int* nx = blockIdx.x ? nidxS : nidxC;
    __shared__ int lds[1024];
    const int t = threadIdx.x;
    const int CH = (N_NODES + 1023) / 1024;   // 49
    const int base = t * CH;
    int s = 0;
    for (int i = 0; i < CH; ++i) { int v = base + i; if (v < N_NODES) s += fl[v]; }
    lds[t] = s;
    for (int off = 1; off < 1024; off <<= 1) {
        __syncthreads();
        int v = (t >= off) ? lds[t - off] : 0;
        __syncthreads();
        lds[t] += v;
    }
    __syncthreads();
    int run = lds[t] - s;
    for (int i = 0; i < CH; ++i) {
        int v = base + i;
        if (v < N_NODES) {
            if (fl[v]) { nx[v] = run; run++; } else nx[v] = -1;
        }
    }
}

// ---------- K8: outputs, iterated by e (all writes coalesced) ----------
__global__ __launch_bounds__(256) void k8_out(const float* __restrict__ attb,
                                              const unsigned char* __restrict__ keepb,
                                              const unsigned* __restrict__ posOf,
                                              const int* __restrict__ ei,
                                              const int* __restrict__ nidxC,
                                              const int* __restrict__ nidxS,
                                              float* __restrict__ out) {
    int e = blockIdx.x * 256 + threadIdx.x;       // grid exact
    unsigned pos = posOf[e];
    float a = attb[pos];                           // 3.2 MB array, L2-resident gather
    int kp = keepb[pos];
    int r = ei[e], c = ei[N_EDGES + e];
    out[e]               = a;
    out[N_EDGES + e]     = kp ? a : 0.f;
    out[2 * N_EDGES + e] = kp ? 0.f : -a;
    if (kp) {
        out[3 * N_EDGES + e] = (float)nidxC[r];
        out[4 * N_EDGES + e] = (float)nidxC[c];
        out[5 * N_EDGES + e] = -1.f;
        out[6 * N_EDGES + e] = -1.f;
    } else {
        out[3 * N_EDGES + e] = -1.f;
        out[4 * N_EDGES + e] = -1.f;
        out[5 * N_EDGES + e] = (float)nidxS[r];
        out[6 * N_EDGES + e] = (float)nidxS[c];
    }
}

extern "C" void kernel_launch(void* const* d_in, const int* in_sizes, int n_in,
                              void* d_out, int out_size, void* d_ws, size_t ws_size,
                              hipStream_t stream) {
    const float* emb   = (const float*)d_in[0];
    const int*   ei    = (const int*)d_in[1];
    const int*   batch = (const int*)d_in[2];
    const float* W1    = (const float*)d_in[3];
    const float* b1    = (const float*)d_in[4];
    const float* W2    = (const float*)d_in[5];
    const float* b2    = (const float*)d_in[6];
    float* out = (float*)d_out;

    char* ws = (char*)d_ws;
    size_t off = 0;
    auto alloc = [&](size_t bytes) -> void* {
        off = (off + 255) & ~(size_t)255;
        void* p = ws + off;
        off += bytes;
        return p;
    };

    float* P              = (float*)alloc((size_t)N_NODES * 256 * 4);   // 51.2 MB
    float* Q              = (float*)alloc((size_t)N_NODES * 256 * 4);   // 51.2 MB
    float* attb           = (float*)alloc((size_t)N_EDGES * 4);
    unsigned* rcbuck      = (unsigned*)alloc(((size_t)N_EDGES + 8) * 4);
    unsigned* ebuck       = (unsigned*)alloc(((size_t)N_EDGES + 8) * 4);
    unsigned* posOf       = (unsigned*)alloc((size_t)N_EDGES * 4);
    unsigned char* keepb  = (unsigned char*)alloc(N_EDGES);
    unsigned char* flags2 = (unsigned char*)alloc((size_t)2 * N_NODES);  // C|S contiguous
    unsigned char* flagC  = flags2;
    unsigned char* flagS  = flags2 + N_NODES;
    int* nidxC            = (int*)alloc((size_t)N_NODES * 4);
    int* nidxS            = (int*)alloc((size_t)N_NODES * 4);
    // zeroed meta block: subdeg(8192) subcursor(8192) deg(512) start(512) kk(512) minmax(2)
    unsigned* meta        = (unsigned*)alloc((2 * NBUCK + 3 * 512 + 2) * 4);
    unsigned* subdeg      = meta;
    unsigned* subcursor   = meta + NBUCK;
    unsigned* deg         = meta + 2 * NBUCK;
    unsigned* start       = meta + 2 * NBUCK + 512;
    unsigned* kk          = meta + 2 * NBUCK + 1024;
    unsigned* minmax      = meta + 2 * NBUCK + 1536;
    unsigned* substart    = (unsigned*)alloc((NBUCK + 1) * 4);   // written by k3
    int* node_start       = (int*)alloc(513 * 4);

    const int EB = (N_EDGES + 255) / 256;       // 3125 (exact)
    const int SB = (N_EDGES + 4095) / 4096;     // 196 count blocks

    hipMemsetAsync(meta, 0, (2 * NBUCK + 3 * 512 + 2) * 4, stream);
    hipMemsetAsync(minmax, 0xFF, 4, stream);                  // min acc = UINT_MAX
    hipMemsetAsync(flags2, 0, (size_t)2 * N_NODES, stream);

    int ldsrows = 78;                                         // 78 KB -> 2 blocks/CU
    if (hipFuncSetAttribute((const void*)k2_edge,
                            hipFuncAttributeMaxDynamicSharedMemorySize,
                            78 * 1024) != hipSuccess) {
        ldsrows = 56;
    }
    const size_t shbytes = (size_t)ldsrows * 1024;

    k0_count<<<SB, 256, 0, stream>>>(ei, batch, subdeg, node_start);
    k3_scan<<<1, 1024, 0, stream>>>(subdeg, substart, deg, start, kk);
    k4a_scatter<<<EB, 256, 0, stream>>>(ei, batch, substart, subcursor, rcbuck, ebuck, posOf);

    dim3 g1((N_NODES + 63) / 64, 4);
    k1_gemm<<<g1, 256, 0, stream>>>(emb, W1, b1, P, Q);

    k2_edge<<<N_GRAPHS, 512, shbytes, stream>>>(P, Q, rcbuck, deg, start,
                                                node_start, W2, b2, attb, minmax, ldsrows);

    k5_select<<<N_GRAPHS, 256, 0, stream>>>(deg, start, kk, attb, ebuck, rcbuck,
                                            minmax, keepb, flagC, flagS);
    k7_nodescan<<<2, 1024, 0, stream>>>(flagC, flagS, nidxC, nidxS);
    k8_out<<<EB, 256, 0, stream>>>(attb, keepb, posOf, ei, nidxC, nidxS, out);
}